// Round 2
// baseline (2292.013 us; speedup 1.0000x reference)
//
#include <hip/hip_runtime.h>
#include <hip/hip_bf16.h>

typedef __hip_bfloat16 bf16;
typedef __attribute__((ext_vector_type(8))) __bf16 bf16x8;
typedef __attribute__((ext_vector_type(4))) float f32x4;

__device__ inline bf16 f2b(float v) { return __float2bfloat16(v); }
__device__ inline float ldf(const float* p) { return *p; }
__device__ inline float ldf(const bf16* p) { return __bfloat162float(*p); }

#define BM 128
#define BN 128
#define BKK 32

// ---------------------------------------------------------------------------
// Batched GEMM: C[z] = A[z] (MxK row-major, lda) * Bt[z]^T (Bt: NxK row-major,
// ldb). Epilogue: optional bias / residual / accumulate-into-C / relu.
// Reg-staged LDS (safe path). M%128==0, N%128==0, K%32==0.
// ---------------------------------------------------------------------------
template<bool HAS_BIAS, bool RELU, bool HAS_RES, bool ACC, bool OUT_BF16>
__global__ __launch_bounds__(256) void gemm_bt(
    const bf16* __restrict__ A, const bf16* __restrict__ Bt, void* __restrict__ Cout,
    const float* __restrict__ bias, const float* __restrict__ res,
    int M, int N, int K, int lda, int ldb, int ldc,
    long sAz, long sBz, long sCz, int biasStride)
{
  alignas(16) __shared__ bf16 As[BM * BKK];
  alignas(16) __shared__ bf16 Bs[BN * BKK];
  const int t = threadIdx.x;
  const int l = t & 63;
  const int w = t >> 6;
  const int z = blockIdx.z;
  A += (long)z * sAz;
  Bt += (long)z * sBz;
  const long cbase = (long)z * sCz;
  const int m0 = blockIdx.x * BM;
  const int n0 = blockIdx.y * BN;

  f32x4 acc[4][4] = {};

  // staging: 512 chunks of 8 bf16 per tile; thread t handles chunks t and t+256
  const int r0 = t >> 2;            // row within first 64
  const int kc = (t & 3) * 8;       // k offset
  const bf16* aP0 = A + (long)(m0 + r0) * lda + kc;
  const bf16* aP1 = aP0 + (long)64 * lda;
  const bf16* bP0 = Bt + (long)(n0 + r0) * ldb + kc;
  const bf16* bP1 = bP0 + (long)64 * ldb;
  bf16* aD0 = As + t * 8;
  bf16* aD1 = As + (t + 256) * 8;
  bf16* bD0 = Bs + t * 8;
  bf16* bD1 = Bs + (t + 256) * 8;

  const int fr = l & 15;            // fragment row (within 16)
  const int fk = (l >> 4) * 8;      // fragment k offset
  const int aRow = (w >> 1) * 64 + fr;
  const int bRow = (w & 1) * 64 + fr;

  for (int kt = 0; kt < K; kt += BKK) {
    const bf16x8 va0 = *(const bf16x8*)(aP0 + kt);
    const bf16x8 va1 = *(const bf16x8*)(aP1 + kt);
    const bf16x8 vb0 = *(const bf16x8*)(bP0 + kt);
    const bf16x8 vb1 = *(const bf16x8*)(bP1 + kt);
    __syncthreads();                // prev iter's LDS reads done
    *(bf16x8*)aD0 = va0;
    *(bf16x8*)aD1 = va1;
    *(bf16x8*)bD0 = vb0;
    *(bf16x8*)bD1 = vb1;
    __syncthreads();
    bf16x8 af[4], bv[4];
#pragma unroll
    for (int i = 0; i < 4; ++i)
      af[i] = *(const bf16x8*)(As + (aRow + i * 16) * BKK + fk);
#pragma unroll
    for (int j = 0; j < 4; ++j)
      bv[j] = *(const bf16x8*)(Bs + (bRow + j * 16) * BKK + fk);
#pragma unroll
    for (int i = 0; i < 4; ++i)
#pragma unroll
      for (int j = 0; j < 4; ++j)
        acc[i][j] = __builtin_amdgcn_mfma_f32_16x16x32_bf16(af[i], bv[j], acc[i][j], 0, 0, 0);
  }

  const float* bz = HAS_BIAS ? (bias + (long)z * biasStride) : nullptr;
  float* cf = (float*)Cout;
  bf16* cb = (bf16*)Cout;
#pragma unroll
  for (int i = 0; i < 4; ++i) {
    const int mb = m0 + (w >> 1) * 64 + i * 16 + ((l >> 4) << 2);
#pragma unroll
    for (int j = 0; j < 4; ++j) {
      const int nc = n0 + (w & 1) * 64 + j * 16 + (l & 15);
      const float bvv = HAS_BIAS ? bz[nc] : 0.f;
#pragma unroll
      for (int r = 0; r < 4; ++r) {
        const int m = mb + r;
        const long off = cbase + (long)m * ldc + nc;
        float v = acc[i][j][r] + bvv;
        if (HAS_RES) v += res[(long)m * N + nc];
        if (ACC) v += cf[off];
        if (RELU) v = fmaxf(v, 0.f);
        if (OUT_BF16) cb[off] = f2b(v);
        else cf[off] = v;
      }
    }
  }
}

// ---------------------------------------------------------------------------
template<typename ST>
__global__ __launch_bounds__(256) void transpose_to_bf16(
    const ST* __restrict__ in, bf16* __restrict__ out, int R, int C, long sIn, long sOut)
{
  __shared__ bf16 tile[32][33];
  const int z = blockIdx.z;
  in += (long)z * sIn;
  out += (long)z * sOut;
  const int tx = threadIdx.x & 31, ty = threadIdx.x >> 5;
  const int c0 = blockIdx.x * 32, r0 = blockIdx.y * 32;
#pragma unroll
  for (int i = 0; i < 4; ++i)
    tile[ty + i * 8][tx] = f2b(ldf(in + (long)(r0 + ty + i * 8) * C + c0 + tx));
  __syncthreads();
#pragma unroll
  for (int i = 0; i < 4; ++i)
    out[(long)(c0 + ty + i * 8) * R + r0 + tx] = tile[tx][ty + i * 8];
}

__global__ __launch_bounds__(256) void cast_f32_bf16(
    const float* __restrict__ in, bf16* __restrict__ out, long n)
{
  long i = (long)blockIdx.x * 256 + threadIdx.x;
  const long st = (long)gridDim.x * 256;
  for (; i < n; i += st) out[i] = f2b(in[i]);
}

__global__ __launch_bounds__(256) void fill_sentinel(float* __restrict__ out, long n)
{
  long i = (long)blockIdx.x * 256 + threadIdx.x;
  const long st = (long)gridDim.x * 256;
  for (; i < n; i += st) out[i] = 1.0e6f;
}

// one wave per row of 1024 scores: scale, optional causal mask, softmax, bf16
__global__ __launch_bounds__(256) void softmax_rows(
    const float* __restrict__ Sc, bf16* __restrict__ Aw, float scale, int causal)
{
  const int row = blockIdx.x * 4 + (threadIdx.x >> 6);
  const int l = threadIdx.x & 63;
  const int s = row & 1023;
  const float* rp = Sc + (long)row * 1024;
  float v[16];
  float mx = -3.4e38f;
#pragma unroll
  for (int i = 0; i < 16; ++i) {
    const int tc = i * 64 + l;
    float x = rp[tc] * scale;
    if (causal && tc > s) x = -3.4e38f;
    v[i] = x;
    mx = fmaxf(mx, x);
  }
#pragma unroll
  for (int d = 1; d < 64; d <<= 1) mx = fmaxf(mx, __shfl_xor(mx, d));
  float sum = 0.f;
#pragma unroll
  for (int i = 0; i < 16; ++i) {
    const float e = (v[i] > -1e37f) ? __expf(v[i] - mx) : 0.f;
    v[i] = e;
    sum += e;
  }
#pragma unroll
  for (int d = 1; d < 64; d <<= 1) sum += __shfl_xor(sum, d);
  const float inv = 1.f / sum;
  bf16* op = Aw + (long)row * 1024;
#pragma unroll
  for (int i = 0; i < 16; ++i) op[i * 64 + l] = f2b(v[i] * inv);
}

// one wave per row (D=512); writes fp32 and/or bf16 outputs
__global__ __launch_bounds__(256) void layernorm_k(
    const float* __restrict__ X, const float* __restrict__ g, const float* __restrict__ b,
    float* __restrict__ Yf, bf16* __restrict__ Yb)
{
  const int row = blockIdx.x * 4 + (threadIdx.x >> 6);
  const int l = threadIdx.x & 63;
  const float* xp = X + (long)row * 512;
  float v[8];
  float s = 0.f;
#pragma unroll
  for (int i = 0; i < 8; ++i) { v[i] = xp[i * 64 + l]; s += v[i]; }
#pragma unroll
  for (int d = 1; d < 64; d <<= 1) s += __shfl_xor(s, d);
  const float mean = s * (1.f / 512.f);
  float vs = 0.f;
#pragma unroll
  for (int i = 0; i < 8; ++i) { const float dv = v[i] - mean; vs += dv * dv; }
#pragma unroll
  for (int d = 1; d < 64; d <<= 1) vs += __shfl_xor(vs, d);
  const float rstd = rsqrtf(vs * (1.f / 512.f) + 1e-5f);
#pragma unroll
  for (int i = 0; i < 8; ++i) {
    const int c = i * 64 + l;
    const float y = (v[i] - mean) * rstd * g[c] + b[c];
    if (Yf) Yf[(long)row * 512 + c] = y;
    if (Yb) Yb[(long)row * 512 + c] = f2b(y);
  }
}

__global__ void beff_init_k(const float* __restrict__ bfv, float* __restrict__ beff)
{
  const int e = blockIdx.x * 256 + threadIdx.x;
  if (e < 512) beff[e] = bfv[e];
}

__global__ void beff_accum_k(const float* __restrict__ bo, const float* __restrict__ wf,
                             float* __restrict__ beff)
{
  const int e = blockIdx.x * 256 + threadIdx.x;
  const int g0 = blockIdx.y * 256;
  float s = 0.f;
  for (int gg = 0; gg < 256; ++gg) s += bo[g0 + gg] * wf[(long)(g0 + gg) * 512 + e];
  atomicAdd(&beff[e], s);
}

// ---------------------------------------------------------------------------
template<bool B_, bool R_, bool S_, bool AC, bool O_>
static inline void gemmL(hipStream_t st, int M, int N, int K,
                         const bf16* A, int lda, long sAz,
                         const bf16* Bt, int ldb, long sBz,
                         void* C, int ldc, long sCz,
                         int batch, const float* bias, int biasStride, const float* res)
{
  dim3 g(M / BM, N / BN, batch);
  gemm_bt<B_, R_, S_, AC, O_><<<g, dim3(256), 0, st>>>(
      A, Bt, C, bias, res, M, N, K, lda, ldb, ldc, sAz, sBz, sCz, biasStride);
}

extern "C" void kernel_launch(void* const* d_in, const int* in_sizes, int n_in,
                              void* d_out, int out_size, void* d_ws, size_t ws_size,
                              hipStream_t stream)
{
  (void)in_sizes; (void)n_in;

  const float* x = (const float*)d_in[0];
  const float* enc = (const float*)d_in[1];
  const float* ln_g[3] = {(const float*)d_in[22], (const float*)d_in[24], (const float*)d_in[26]};
  const float* ln_b[3] = {(const float*)d_in[23], (const float*)d_in[25], (const float*)d_in[27]};
  const float* fc1_w = (const float*)d_in[28];
  const float* fc1_b = (const float*)d_in[29];
  const float* fc2_w = (const float*)d_in[30];
  const float* fc2_b = (const float*)d_in[31];

  const long MT = 4096;                 // B*S rows
  const long SD = 1024L * 512;          // per-b [1024,512] slice
  const long ST = 1024L * 1024;         // per-b score block

  char* wp = (char*)d_ws;
  auto alloc = [&](long bytes) -> void* {
    void* p = (void*)wp;
    wp += (bytes + 255) & ~255L;
    return p;
  };

  // ---- persistent buffers (~76 MB) ----
  bf16* Xb  = (bf16*)alloc(MT * 512 * 2);
  bf16* Eb  = (bf16*)alloc(MT * 512 * 2);
  float* x1f = (float*)alloc(MT * 512 * 4);
  bf16*  x1b = (bf16*)alloc(MT * 512 * 2);
  float* x2f = (float*)alloc(MT * 512 * 4);
  bf16*  x2b = (bf16*)alloc(MT * 512 * 2);
  float* Sf  = (float*)alloc(MT * 512 * 4);
  bf16* wT[2][3];
  bf16* W2t[2];
  float* beff[2];
  for (int p = 0; p < 2; ++p) {
    for (int q = 0; q < 3; ++q) wT[p][q] = (bf16*)alloc(8L * 512 * 512 * 2);
    W2t[p] = (bf16*)alloc(512L * 4096 * 2);
    beff[p] = (float*)alloc(512 * 4);
  }
  bf16* fc1T = (bf16*)alloc(2048L * 512 * 2);
  bf16* fc2T = (bf16*)alloc(512L * 2048 * 2);

  // ---- reusable pool (44 MB) ----
  char* pool = (char*)alloc(44L * 1024 * 1024);

  if ((size_t)(wp - (char*)d_ws) > ws_size) {
    fill_sentinel<<<dim3(2048), dim3(256), 0, stream>>>((float*)d_out, (long)out_size);
    return;
  }

  // pool views — attention phase
  bf16* Qh  = (bf16*)(pool);                       // 4 MB  [4096,512]
  bf16* Kh  = (bf16*)(pool + (4L << 20));          // 4 MB
  bf16* Vh  = (bf16*)(pool + (8L << 20));          // 4 MB
  bf16* Vth = (bf16*)(pool + (12L << 20));         // 4 MB  [4][512][1024]
  float* sc = (float*)(pool + (16L << 20));        // 16 MB [4][1024][1024] fp32
  bf16* Aw  = (bf16*)(pool + (32L << 20));         // 8 MB
  bf16* Oh  = (bf16*)(pool + (40L << 20));         // 4 MB  [4096,512]
  // pool views — prep phase
  bf16* wfT = (bf16*)(pool);                       // 4 MB [512,4096]
  bf16* woB = (bf16*)(pool + (4L << 20));          // 4 MB
  // pool views — FFN phase
  bf16* Hb  = (bf16*)(pool);                       // 16 MB [4096,2048]

  // ---------------- prep ----------------
  cast_f32_bf16<<<dim3(1024), dim3(256), 0, stream>>>(x, Xb, MT * 512);
  cast_f32_bf16<<<dim3(1024), dim3(256), 0, stream>>>(enc, Eb, MT * 512);

  for (int p = 0; p < 2; ++p) {
    const int base = (p == 0) ? 2 : 12;
    const float* wq = (const float*)d_in[base + 0];
    const float* wk = (const float*)d_in[base + 2];
    const float* wv = (const float*)d_in[base + 4];
    const float* wo = (const float*)d_in[base + 6];
    const float* bo = (const float*)d_in[base + 7];
    const float* wf = (const float*)d_in[base + 8];
    const float* bfv = (const float*)d_in[base + 9];
    transpose_to_bf16<float><<<dim3(16, 16, 8), dim3(256), 0, stream>>>(wq, wT[p][0], 512, 512, 262144, 262144);
    transpose_to_bf16<float><<<dim3(16, 16, 8), dim3(256), 0, stream>>>(wk, wT[p][1], 512, 512, 262144, 262144);
    transpose_to_bf16<float><<<dim3(16, 16, 8), dim3(256), 0, stream>>>(wv, wT[p][2], 512, 512, 262144, 262144);
    transpose_to_bf16<float><<<dim3(16, 128, 1), dim3(256), 0, stream>>>(wf, wfT, 4096, 512, 0, 0);
    cast_f32_bf16<<<dim3(1024), dim3(256), 0, stream>>>(wo, woB, 8L * 512 * 512);
    // W2t[e*4096 + h*512 + f] = sum_g wf[h*512+g, e] * wo[h, f, g]
    gemmL<false, false, false, false, true>(stream, 512, 512, 512,
        wfT, 4096, 512, woB, 512, 262144,
        W2t[p], 4096, 512, 8, nullptr, 0, nullptr);
    beff_init_k<<<dim3(2), dim3(256), 0, stream>>>(bfv, beff[p]);
    beff_accum_k<<<dim3(2, 16), dim3(256), 0, stream>>>(bo, wf, beff[p]);
  }
  transpose_to_bf16<float><<<dim3(64, 16, 1), dim3(256), 0, stream>>>(fc1_w, fc1T, 512, 2048, 0, 0);
  transpose_to_bf16<float><<<dim3(16, 64, 1), dim3(256), 0, stream>>>(fc2_w, fc2T, 2048, 512, 0, 0);

  // ---------------- attention ----------------
  auto run_attn = [&](int base, const bf16* qin, const bf16* kvin,
                      const float* resid, int p, int causal) {
    const float* bq = (const float*)d_in[base + 1];
    const float* bk = (const float*)d_in[base + 3];
    const float* bv = (const float*)d_in[base + 5];
    for (int h = 0; h < 8; ++h) {
      const long wOff = (long)h * 262144;
      gemmL<true, false, false, false, true>(stream, 4096, 512, 512,
          qin, 512, 0, wT[p][0] + wOff, 512, 0, Qh, 512, 0, 1, bq + h * 512, 0, nullptr);
      gemmL<true, false, false, false, true>(stream, 4096, 512, 512,
          kvin, 512, 0, wT[p][1] + wOff, 512, 0, Kh, 512, 0, 1, bk + h * 512, 0, nullptr);
      gemmL<true, false, false, false, true>(stream, 4096, 512, 512,
          kvin, 512, 0, wT[p][2] + wOff, 512, 0, Vh, 512, 0, 1, bv + h * 512, 0, nullptr);
      transpose_to_bf16<bf16><<<dim3(16, 32, 4), dim3(256), 0, stream>>>(Vh, Vth, 1024, 512, SD, SD);
      // scores (fp32) for 4 b's
      gemmL<false, false, false, false, false>(stream, 1024, 1024, 512,
          Qh, 512, SD, Kh, 512, SD, sc, 1024, ST, 4, nullptr, 0, nullptr);
      softmax_rows<<<dim3(1024), dim3(256), 0, stream>>>(sc, Aw, 0.04419417382415922f, causal);
      // PV
      gemmL<false, false, false, false, true>(stream, 1024, 512, 1024,
          Aw, 1024, ST, Vth, 1024, SD, Oh, 512, SD, 4, nullptr, 0, nullptr);
      // accumulate head's contribution through combined out-proj weight
      if (h == 0)
        gemmL<true, false, true, false, false>(stream, 4096, 512, 512,
            Oh, 512, 0, W2t[p] + h * 512, 4096, 0, Sf, 512, 0, 1, beff[p], 0, resid);
      else
        gemmL<false, false, false, true, false>(stream, 4096, 512, 512,
            Oh, 512, 0, W2t[p] + h * 512, 4096, 0, Sf, 512, 0, 1, nullptr, 0, nullptr);
    }
  };

  run_attn(2, Xb, Xb, x, 0, 1);
  layernorm_k<<<dim3(1024), dim3(256), 0, stream>>>(Sf, ln_g[0], ln_b[0], x1f, x1b);

  run_attn(12, x1b, Eb, x1f, 1, 0);
  layernorm_k<<<dim3(1024), dim3(256), 0, stream>>>(Sf, ln_g[1], ln_b[1], x2f, x2b);

  // ---------------- FFN ----------------
  gemmL<true, true, false, false, true>(stream, 4096, 2048, 512,
      x2b, 512, 0, fc1T, 512, 0, Hb, 2048, 0, 1, fc1_b, 0, nullptr);
  gemmL<true, false, true, false, false>(stream, 4096, 512, 2048,
      Hb, 2048, 0, fc2T, 2048, 0, Sf, 512, 0, 1, fc2_b, 0, x2f);
  layernorm_k<<<dim3(1024), dim3(256), 0, stream>>>(Sf, ln_g[2], ln_b[2], (float*)d_out, nullptr);
}

// Round 3
// 1459.183 us; speedup vs baseline: 1.5708x; 1.5708x over previous
//
#include <hip/hip_runtime.h>
#include <hip/hip_bf16.h>

typedef __hip_bfloat16 bf16;
typedef __attribute__((ext_vector_type(8))) __bf16 bf16x8;
typedef __attribute__((ext_vector_type(4))) float f32x4;

typedef const __attribute__((address_space(1))) void cg_void;
typedef __attribute__((address_space(3))) void lds_void;

__device__ inline float b2f(bf16 v) { return __bfloat162float(v); }
__device__ inline bf16 f2b(float v) { return __float2bfloat16(v); }
__device__ inline float ldf(const float* p) { return *p; }
__device__ inline float ldf(const bf16* p) { return __bfloat162float(*p); }

#define BKK 32

// ---------------------------------------------------------------------------
// Batched GEMM: C[z] = A[z] (M x K, row-major lda) * Bt[z]^T (Bt: N x K rows,
// ldb). Per-z offsets: (z/zdiv)*Hi + (z%zdiv)*Lo for A, B, C independently.
// BM=128 fixed; BN_ in {128, 64}. global_load_lds (width 16) staging.
// ---------------------------------------------------------------------------
template<int BN_, bool BIAS, bool RELU, bool OUT_BF16>
__global__ __launch_bounds__(256) void gemm_bt(
    const bf16* __restrict__ A, const bf16* __restrict__ Bt, void* __restrict__ Cout,
    const float* __restrict__ bias,
    int M, int N, int K, int lda, int ldb, int ldc,
    long aHi, long aLo, long bHi, long bLo, long cHi, long cLo, int zdiv)
{
  alignas(16) __shared__ bf16 As[128 * BKK];
  alignas(16) __shared__ bf16 Bs[BN_ * BKK];
  const int t = threadIdx.x;
  const int l = t & 63;
  const int w = t >> 6;
  const int z = blockIdx.z;
  const int zq = z / zdiv, zr = z % zdiv;
  A += (long)zq * aHi + (long)zr * aLo;
  Bt += (long)zq * bHi + (long)zr * bLo;
  const long cbase = (long)zq * cHi + (long)zr * cLo;
  const int m0 = blockIdx.x * 128;
  const int n0 = blockIdx.y * BN_;

  constexpr int NJ = BN_ / 32;
  f32x4 acc[4][NJ] = {};

  // staging addresses (16B per thread per chunk)
  const int r0 = t >> 2;
  const int kc = (t & 3) * 8;
  const bf16* aP0 = A + (long)(m0 + r0) * lda + kc;
  const bf16* aP1 = aP0 + (long)64 * lda;
  bf16* aD0 = As + t * 8;
  bf16* aD1 = As + (t + 256) * 8;
  const bf16* bP0 = Bt + (long)(n0 + r0) * ldb + kc;
  bf16* bD0 = Bs + t * 8;
  const bf16* bP1 = bP0 + (long)64 * ldb;
  bf16* bD1 = Bs + (t + 256) * 8;

  const int fr = l & 15;
  const int fk = (l >> 4) * 8;
  const int aRow = (w >> 1) * 64 + fr;
  const int bRow = (w & 1) * (BN_ / 2) + fr;

  for (int kt = 0; kt < K; kt += BKK) {
    __builtin_amdgcn_global_load_lds((cg_void*)(aP0 + kt), (lds_void*)aD0, 16, 0, 0);
    __builtin_amdgcn_global_load_lds((cg_void*)(aP1 + kt), (lds_void*)aD1, 16, 0, 0);
    __builtin_amdgcn_global_load_lds((cg_void*)(bP0 + kt), (lds_void*)bD0, 16, 0, 0);
    if constexpr (BN_ == 128)
      __builtin_amdgcn_global_load_lds((cg_void*)(bP1 + kt), (lds_void*)bD1, 16, 0, 0);
    __syncthreads();   // compiler drains vmcnt before barrier -> LDS data ready
    bf16x8 af[4], bv[NJ];
#pragma unroll
    for (int i = 0; i < 4; ++i)
      af[i] = *(const bf16x8*)(As + (aRow + i * 16) * BKK + fk);
#pragma unroll
    for (int j = 0; j < NJ; ++j)
      bv[j] = *(const bf16x8*)(Bs + (bRow + j * 16) * BKK + fk);
#pragma unroll
    for (int i = 0; i < 4; ++i)
#pragma unroll
      for (int j = 0; j < NJ; ++j)
        acc[i][j] = __builtin_amdgcn_mfma_f32_16x16x32_bf16(af[i], bv[j], acc[i][j], 0, 0, 0);
    __syncthreads();   // LDS reads done before next iter's overwrite
  }

  float* cf = (float*)Cout;
  bf16* cb = (bf16*)Cout;
#pragma unroll
  for (int i = 0; i < 4; ++i) {
    const int mb = m0 + (w >> 1) * 64 + i * 16 + ((l >> 4) << 2);
#pragma unroll
    for (int j = 0; j < NJ; ++j) {
      const int nc = n0 + (w & 1) * (BN_ / 2) + j * 16 + fr;
      const float bvv = BIAS ? bias[nc] : 0.f;
#pragma unroll
      for (int r = 0; r < 4; ++r) {
        const int m = mb + r;
        const long off = cbase + (long)m * ldc + nc;
        float vv = acc[i][j][r] + bvv;
        if (RELU) vv = fmaxf(vv, 0.f);
        if (OUT_BF16) cb[off] = f2b(vv);
        else cf[off] = vv;
      }
    }
  }
}

template<int BN_, bool B_, bool R_, bool O_>
static inline void gemmL(hipStream_t st, int M, int N, int K,
                         const bf16* A, int lda, long aHi, long aLo,
                         const bf16* Bt, int ldb, long bHi, long bLo,
                         void* C, int ldc, long cHi, long cLo,
                         int zdiv, int nz, const float* bias)
{
  dim3 g(M / 128, N / BN_, nz);
  gemm_bt<BN_, B_, R_, O_><<<g, dim3(256), 0, st>>>(
      A, Bt, C, bias, M, N, K, lda, ldb, ldc, aHi, aLo, bHi, bLo, cHi, cLo, zdiv);
}

// ---------------------------------------------------------------------------
template<typename ST>
__global__ __launch_bounds__(256) void transpose_to_bf16(
    const ST* __restrict__ in, bf16* __restrict__ out, int R, int C, long sIn, long sOut)
{
  __shared__ bf16 tile[32][33];
  const int z = blockIdx.z;
  in += (long)z * sIn;
  out += (long)z * sOut;
  const int tx = threadIdx.x & 31, ty = threadIdx.x >> 5;
  const int c0 = blockIdx.x * 32, r0 = blockIdx.y * 32;
#pragma unroll
  for (int i = 0; i < 4; ++i)
    tile[ty + i * 8][tx] = f2b(ldf(in + (long)(r0 + ty + i * 8) * C + c0 + tx));
  __syncthreads();
#pragma unroll
  for (int i = 0; i < 4; ++i)
    out[(long)(c0 + ty + i * 8) * R + r0 + tx] = tile[tx][ty + i * 8];
}

__global__ __launch_bounds__(256) void cast4_k(
    const float* __restrict__ in, bf16* __restrict__ out, long n4)
{
  long i = (long)blockIdx.x * 256 + threadIdx.x;
  const long st = (long)gridDim.x * 256;
  for (; i < n4; i += st) {
    const float4 v = ((const float4*)in)[i];
    bf16* o = out + i * 4;
    o[0] = f2b(v.x); o[1] = f2b(v.y); o[2] = f2b(v.z); o[3] = f2b(v.w);
  }
}

__global__ __launch_bounds__(256) void fill_sentinel(float* __restrict__ out, long n)
{
  long i = (long)blockIdx.x * 256 + threadIdx.x;
  const long st = (long)gridDim.x * 256;
  for (; i < n; i += st) out[i] = 1.0e6f;
}

// in-place softmax over 1024-wide rows of bf16 scores; arg = (S + v[t]) * scale
__global__ __launch_bounds__(256) void softmax_rows(
    bf16* __restrict__ S, const float* __restrict__ v, float scale, int causal)
{
  const int r = blockIdx.x * 4 + (threadIdx.x >> 6);
  const int l = threadIdx.x & 63;
  const int zl = r >> 10, s = r & 1023;
  bf16* row = S + (long)r * 1024;
  const float* vp = v + (zl >> 2) * 4096 + (zl & 3) * 1024;
  const int t0 = l * 16;
  bf16x8* rp = (bf16x8*)(row + t0);
  const bf16x8 a0 = rp[0], a1 = rp[1];
  float xx[16];
#pragma unroll
  for (int j = 0; j < 8; ++j) { xx[j] = (float)a0[j]; xx[8 + j] = (float)a1[j]; }
  float mx = -3.4e38f;
#pragma unroll
  for (int k = 0; k < 16; ++k) {
    const int tt = t0 + k;
    float val = (xx[k] + vp[tt]) * scale;
    if (causal && tt > s) val = -3.4e38f;
    xx[k] = val;
    mx = fmaxf(mx, val);
  }
#pragma unroll
  for (int d = 1; d < 64; d <<= 1) mx = fmaxf(mx, __shfl_xor(mx, d));
  float sum = 0.f;
#pragma unroll
  for (int k = 0; k < 16; ++k) {
    const float e = (xx[k] > -1e37f) ? __expf(xx[k] - mx) : 0.f;
    xx[k] = e;
    sum += e;
  }
#pragma unroll
  for (int d = 1; d < 64; d <<= 1) sum += __shfl_xor(sum, d);
  const float inv = 1.f / sum;
  bf16x8 r0v, r1v;
#pragma unroll
  for (int j = 0; j < 8; ++j) {
    r0v[j] = (__bf16)(xx[j] * inv);
    r1v[j] = (__bf16)(xx[8 + j] * inv);
  }
  rp[0] = r0v;
  rp[1] = r1v;
}

// fused: sum split-K partials + beff + residual -> LayerNorm -> bf16/fp32 out
__global__ __launch_bounds__(256) void ln_fused(
    const float* __restrict__ parts, long zstride, int nz,
    const float* __restrict__ beff, const float* __restrict__ resF,
    const bf16* __restrict__ resB, const float* __restrict__ g,
    const float* __restrict__ b, bf16* __restrict__ outB, float* __restrict__ outF)
{
  const int m = blockIdx.x * 4 + (threadIdx.x >> 6);
  const int l = threadIdx.x & 63;
  float vv[8];
  float s = 0.f;
#pragma unroll
  for (int i = 0; i < 8; ++i) {
    const int c = i * 64 + l;
    float acc = beff[c];
    if (resF) acc += resF[(long)m * 512 + c];
    else acc += b2f(resB[(long)m * 512 + c]);
    for (int zz = 0; zz < nz; ++zz) acc += parts[zz * zstride + (long)m * 512 + c];
    vv[i] = acc;
    s += acc;
  }
#pragma unroll
  for (int d = 1; d < 64; d <<= 1) s += __shfl_xor(s, d);
  const float mean = s * (1.f / 512.f);
  float vs = 0.f;
#pragma unroll
  for (int i = 0; i < 8; ++i) { const float dv = vv[i] - mean; vs += dv * dv; }
#pragma unroll
  for (int d = 1; d < 64; d <<= 1) vs += __shfl_xor(vs, d);
  const float rstd = rsqrtf(vs * (1.f / 512.f) + 1e-5f);
#pragma unroll
  for (int i = 0; i < 8; ++i) {
    const int c = i * 64 + l;
    const float y = (vv[i] - mean) * rstd * g[c] + b[c];
    if (outB) outB[(long)m * 512 + c] = f2b(y);
    if (outF) outF[(long)m * 512 + c] = y;
  }
}

// wkbq[h][d] = sum_f wk[h,d,f] * bq[h,f]
__global__ void wkbq_k(const float* __restrict__ wk, const float* __restrict__ bq,
                       float* __restrict__ o)
{
  const int id = blockIdx.x * 256 + threadIdx.x;  // 4096
  const int h = id >> 9, d = id & 511;
  float s = 0.f;
  const float* wp = wk + (long)h * 262144 + (long)d * 512;
  const float* bp = bq + h * 512;
  for (int f = 0; f < 512; ++f) s += wp[f] * bp[f];
  o[id] = s;
}

// v[h][m] = sum_d kvB[m,d] * wkbq[h,d]
__global__ __launch_bounds__(256) void rank1_v(
    const bf16* __restrict__ kvB, const float* __restrict__ wkbq, float* __restrict__ v)
{
  const int m = blockIdx.x * 4 + (threadIdx.x >> 6);
  const int l = threadIdx.x & 63;
  const bf16x8 row = *(const bf16x8*)(kvB + (long)m * 512 + l * 8);
  float rf[8];
#pragma unroll
  for (int j = 0; j < 8; ++j) rf[j] = (float)row[j];
  for (int h = 0; h < 8; ++h) {
    const float* wp = wkbq + h * 512 + l * 8;
    float p = 0.f;
#pragma unroll
    for (int j = 0; j < 8; ++j) p += rf[j] * wp[j];
#pragma unroll
    for (int d = 1; d < 64; d <<= 1) p += __shfl_xor(p, d);
    if (l == 0) v[(long)h * 4096 + m] = p;
  }
}

// beff[e] = bf[e] + sum_hg bo[hg]*wf[hg,e] + sum_hf bv[hf]*W2t[e,hf]
__global__ void beff_k(const float* __restrict__ bf_, const float* __restrict__ bo,
                       const float* __restrict__ wf, const float* __restrict__ bv,
                       const bf16* __restrict__ W2t, float* __restrict__ beff)
{
  const int e = blockIdx.x * 256 + threadIdx.x;  // 512
  float s = bf_[e];
  for (int hg = 0; hg < 4096; ++hg) s += bo[hg] * wf[(long)hg * 512 + e];
  const bf16* wrow = W2t + (long)e * 4096;
  for (int hf = 0; hf < 4096; ++hf) s += bv[hf] * b2f(wrow[hf]);
  beff[e] = s;
}

// ---------------------------------------------------------------------------
extern "C" void kernel_launch(void* const* d_in, const int* in_sizes, int n_in,
                              void* d_out, int out_size, void* d_ws, size_t ws_size,
                              hipStream_t stream)
{
  (void)in_sizes; (void)n_in;
  const float* x = (const float*)d_in[0];
  const float* enc = (const float*)d_in[1];
  const float* ln_g[3] = {(const float*)d_in[22], (const float*)d_in[24], (const float*)d_in[26]};
  const float* ln_b[3] = {(const float*)d_in[23], (const float*)d_in[25], (const float*)d_in[27]};
  const float* fc1_w = (const float*)d_in[28];
  const float* fc1_b = (const float*)d_in[29];
  const float* fc2_w = (const float*)d_in[30];
  const float* fc2_b = (const float*)d_in[31];

  const float scale = 0.044194173824159216f;  // 1/sqrt(512)
  char* base = (char*)d_ws;
  const long MB = 1024 * 1024;

  // ---- layout (113 MB) ----
  bf16* Xb    = (bf16*)(base + 0 * MB);        // 4 MB [4096,512]
  bf16* Eb    = (bf16*)(base + 4 * MB);        // 4 MB
  bf16* x1b   = (bf16*)(base + 8 * MB);        // 4 MB
  bf16* x2b   = (bf16*)(base + 12 * MB);       // 4 MB
  bf16* fc1T  = (bf16*)(base + 16 * MB);       // 2 MB [2048,512]
  bf16* fc2T  = (bf16*)(base + 18 * MB);       // 2 MB [512,2048]
  float* vbuf = (float*)(base + 20 * MB);      // 128 KB [8][4096]
  float* wkbq = (float*)(base + 20 * MB + 256 * 1024);   // 16 KB
  float* beff = (float*)(base + 20 * MB + 512 * 1024);   // 2 KB
  bf16* XT    = (bf16*)(base + 21 * MB);       // 4 MB [4][512][1024]
  bf16* WqkT  = (bf16*)(base + 25 * MB);       // 4 MB [8*512,512]
  bf16* W3cat = (bf16*)(base + 29 * MB);       // 4 MB [512,4096]
  char* Treg  = base + 33 * MB;                // 32 MB: T [4096,4096] bf16 | partials [4][4096][512] f32
  char* screg = base + 65 * MB;                // 16 MB: scores chunk | (prep: W2t@+0, wfT@+4MB)
  char* axreg = base + 81 * MB;                // 32 MB: AX [4096,4096] | (prep: wqB,wkB,wvB,woB) | Hb

  bf16* T     = (bf16*)Treg;
  float* parts = (float*)Treg;
  bf16* scores = (bf16*)screg;
  bf16* W2t   = (bf16*)screg;
  bf16* wfT   = (bf16*)(screg + 4 * MB);
  bf16* AX    = (bf16*)axreg;
  bf16* wqB   = (bf16*)axreg;
  bf16* wkB   = (bf16*)(axreg + 4 * MB);
  bf16* wvB   = (bf16*)(axreg + 8 * MB);
  bf16* woB   = (bf16*)(axreg + 12 * MB);
  bf16* Hb    = (bf16*)axreg;

  if (ws_size < (size_t)(113 * MB)) {
    fill_sentinel<<<dim3(2048), dim3(256), 0, stream>>>((float*)d_out, (long)out_size);
    return;
  }

  // ---- global prep ----
  cast4_k<<<dim3(512), dim3(256), 0, stream>>>(x, Xb, 4096L * 512 / 4);
  cast4_k<<<dim3(512), dim3(256), 0, stream>>>(enc, Eb, 4096L * 512 / 4);
  transpose_to_bf16<float><<<dim3(64, 16, 1), dim3(256), 0, stream>>>(fc1_w, fc1T, 512, 2048, 0, 0);
  transpose_to_bf16<float><<<dim3(16, 64, 1), dim3(256), 0, stream>>>(fc2_w, fc2T, 2048, 512, 0, 0);

  auto run_attn = [&](int ib, const bf16* qB, const bf16* kvB,
                      const float* resF, const bf16* resB, int causal,
                      const float* lg, const float* lb, bf16* outB) {
    const float* wq = (const float*)d_in[ib + 0];
    const float* bq = (const float*)d_in[ib + 1];
    const float* wk = (const float*)d_in[ib + 2];
    const float* wv = (const float*)d_in[ib + 4];
    const float* bv = (const float*)d_in[ib + 5];
    const float* wo = (const float*)d_in[ib + 6];
    const float* bo = (const float*)d_in[ib + 7];
    const float* wf = (const float*)d_in[ib + 8];
    const float* bfv = (const float*)d_in[ib + 9];

    // --- weight prep (scratch lives in scores/AX regions, both dead here) ---
    cast4_k<<<dim3(512), dim3(256), 0, stream>>>(wq, wqB, 2097152 / 4);
    cast4_k<<<dim3(512), dim3(256), 0, stream>>>(wk, wkB, 2097152 / 4);
    cast4_k<<<dim3(512), dim3(256), 0, stream>>>(wv, wvB, 2097152 / 4);
    cast4_k<<<dim3(512), dim3(256), 0, stream>>>(wo, woB, 2097152 / 4);
    transpose_to_bf16<float><<<dim3(16, 128, 1), dim3(256), 0, stream>>>(wf, wfT, 4096, 512, 0, 0);
    // W2t[e][h*512+f] = sum_g wfT[e][h*512+g] * wo[h][f][g]
    gemmL<64, false, false, true>(stream, 512, 512, 512,
        wfT, 4096, 512, 0, woB, 512, 262144, 0, W2t, 4096, 512, 0, 1, 8, nullptr);
    beff_k<<<dim3(2), dim3(256), 0, stream>>>(bfv, bo, wf, bv, W2t, beff);
    // WqkT[h*512+d2][d1] = sum_f wk[h,d2,f] * wq[h,d1,f]
    gemmL<64, false, false, true>(stream, 512, 512, 512,
        wkB, 512, 262144, 0, wqB, 512, 262144, 0, WqkT, 512, 262144, 0, 1, 8, nullptr);
    // W3cat[e][h*512+d] = sum_f W2t[e][h*512+f] * wv[h,d,f]
    gemmL<64, false, false, true>(stream, 512, 512, 512,
        W2t, 4096, 512, 0, wvB, 512, 262144, 0, W3cat, 4096, 512, 0, 1, 8, nullptr);
    wkbq_k<<<dim3(16), dim3(256), 0, stream>>>(wk, bq, wkbq);
    rank1_v<<<dim3(1024), dim3(256), 0, stream>>>(kvB, wkbq, vbuf);
    // XT[b][d][t] = kvB[b*1024+t][d]
    transpose_to_bf16<bf16><<<dim3(16, 32, 4), dim3(256), 0, stream>>>(
        kvB, XT, 1024, 512, 524288, 524288);
    // T = qB @ Wqk  [4096, 4096]
    gemmL<128, false, false, true>(stream, 4096, 4096, 512,
        qB, 512, 0, 0, WqkT, 512, 0, 0, T, 4096, 0, 0, 1, 1, nullptr);

    // --- chunks of 2 heads x 4 batches ---
    for (int c = 0; c < 4; ++c) {
      // S = T_slice @ kv_slice^T(stored as rows)  -> bf16 scores
      gemmL<128, false, false, true>(stream, 1024, 1024, 512,
          T + 2 * c * 512, 4096, 512, 4194304,
          kvB, 512, 0, 524288,
          scores, 1024, 4194304, 1048576, 4, 8, nullptr);
      softmax_rows<<<dim3(2048), dim3(256), 0, stream>>>(
          scores, vbuf + 2 * c * 4096, scale, causal);
      // AX = P @ Xk  (Bt = XT[b])
      gemmL<64, false, false, true>(stream, 1024, 512, 1024,
          scores, 1024, 4194304, 1048576,
          XT, 1024, 0, 524288,
          AX + 2 * c * 512, 4096, 512, 4194304, 4, 8, nullptr);
    }
    // out partials = AX @ W3cat^T (split-K=4)
    gemmL<64, false, false, false>(stream, 4096, 512, 1024,
        AX, 4096, 1024, 0, W3cat, 4096, 1024, 0,
        parts, 512, 2097152, 0, 1, 4, nullptr);
    ln_fused<<<dim3(1024), dim3(256), 0, stream>>>(
        parts, 2097152, 4, beff, resF, resB, lg, lb, outB, nullptr);
  };

  run_attn(2, Xb, Xb, x, nullptr, 1, ln_g[0], ln_b[0], x1b);
  run_attn(12, x1b, Eb, nullptr, x1b, 0, ln_g[1], ln_b[1], x2b);

  // ---- FFN ----
  gemmL<128, true, true, true>(stream, 4096, 2048, 512,
      x2b, 512, 0, 0, fc1T, 512, 0, 0, Hb, 2048, 0, 0, 1, 1, fc1_b);
  gemmL<64, false, false, false>(stream, 4096, 512, 512,
      Hb, 2048, 512, 0, fc2T, 2048, 512, 0, parts, 512, 2097152, 0, 1, 4, nullptr);
  ln_fused<<<dim3(1024), dim3(256), 0, stream>>>(
      parts, 2097152, 4, fc2_b, nullptr, x2b, ln_g[2], ln_b[2], nullptr, (float*)d_out);
}

// Round 4
// 947.739 us; speedup vs baseline: 2.4184x; 1.5396x over previous
//
#include <hip/hip_runtime.h>
#include <hip/hip_bf16.h>

typedef __hip_bfloat16 bf16;
typedef __attribute__((ext_vector_type(8))) __bf16 bf16x8;
typedef __attribute__((ext_vector_type(4))) float f32x4;

typedef const __attribute__((address_space(1))) void cg_void;
typedef __attribute__((address_space(3))) void lds_void;

__device__ inline float b2f(bf16 v) { return __bfloat162float(v); }
__device__ inline bf16 f2b(float v) { return __float2bfloat16(v); }
__device__ inline float ldf(const float* p) { return *p; }
__device__ inline float ldf(const bf16* p) { return __bfloat162float(*p); }

#define BKK 32

// ---------------------------------------------------------------------------
// Batched GEMM: C[z] = A[z] (M x K, row-major lda) * Bt[z]^T (Bt: N x K rows,
// ldb). Per-z offsets: (z/zdiv)*Hi + (z%zdiv)*Lo for A, B, C independently.
// BM=128 fixed; BN_ in {128, 64}. global_load_lds (width 16) staging.
// ---------------------------------------------------------------------------
template<int BN_, bool BIAS, bool RELU, bool OUT_BF16>
__global__ __launch_bounds__(256) void gemm_bt(
    const bf16* __restrict__ A, const bf16* __restrict__ Bt, void* __restrict__ Cout,
    const float* __restrict__ bias,
    int M, int N, int K, int lda, int ldb, int ldc,
    long aHi, long aLo, long bHi, long bLo, long cHi, long cLo, int zdiv)
{
  alignas(16) __shared__ bf16 As[128 * BKK];
  alignas(16) __shared__ bf16 Bs[BN_ * BKK];
  const int t = threadIdx.x;
  const int l = t & 63;
  const int w = t >> 6;
  const int z = blockIdx.z;
  const int zq = z / zdiv, zr = z % zdiv;
  A += (long)zq * aHi + (long)zr * aLo;
  Bt += (long)zq * bHi + (long)zr * bLo;
  const long cbase = (long)zq * cHi + (long)zr * cLo;
  const int m0 = blockIdx.x * 128;
  const int n0 = blockIdx.y * BN_;

  constexpr int NJ = BN_ / 32;
  f32x4 acc[4][NJ] = {};

  const int r0 = t >> 2;
  const int kc = (t & 3) * 8;
  const bf16* aP0 = A + (long)(m0 + r0) * lda + kc;
  const bf16* aP1 = aP0 + (long)64 * lda;
  bf16* aD0 = As + t * 8;
  bf16* aD1 = As + (t + 256) * 8;
  const bf16* bP0 = Bt + (long)(n0 + r0) * ldb + kc;
  bf16* bD0 = Bs + t * 8;
  const bf16* bP1 = bP0 + (long)64 * ldb;
  bf16* bD1 = Bs + (t + 256) * 8;

  const int fr = l & 15;
  const int fk = (l >> 4) * 8;
  const int aRow = (w >> 1) * 64 + fr;
  const int bRow = (w & 1) * (BN_ / 2) + fr;

  for (int kt = 0; kt < K; kt += BKK) {
    __builtin_amdgcn_global_load_lds((cg_void*)(aP0 + kt), (lds_void*)aD0, 16, 0, 0);
    __builtin_amdgcn_global_load_lds((cg_void*)(aP1 + kt), (lds_void*)aD1, 16, 0, 0);
    __builtin_amdgcn_global_load_lds((cg_void*)(bP0 + kt), (lds_void*)bD0, 16, 0, 0);
    if constexpr (BN_ == 128)
      __builtin_amdgcn_global_load_lds((cg_void*)(bP1 + kt), (lds_void*)bD1, 16, 0, 0);
    __syncthreads();
    bf16x8 af[4], bv[NJ];
#pragma unroll
    for (int i = 0; i < 4; ++i)
      af[i] = *(const bf16x8*)(As + (aRow + i * 16) * BKK + fk);
#pragma unroll
    for (int j = 0; j < NJ; ++j)
      bv[j] = *(const bf16x8*)(Bs + (bRow + j * 16) * BKK + fk);
#pragma unroll
    for (int i = 0; i < 4; ++i)
#pragma unroll
      for (int j = 0; j < NJ; ++j)
        acc[i][j] = __builtin_amdgcn_mfma_f32_16x16x32_bf16(af[i], bv[j], acc[i][j], 0, 0, 0);
    __syncthreads();
  }

  float* cf = (float*)Cout;
  bf16* cb = (bf16*)Cout;
#pragma unroll
  for (int i = 0; i < 4; ++i) {
    const int mb = m0 + (w >> 1) * 64 + i * 16 + ((l >> 4) << 2);
#pragma unroll
    for (int j = 0; j < NJ; ++j) {
      const int nc = n0 + (w & 1) * (BN_ / 2) + j * 16 + fr;
      const float bvv = BIAS ? bias[nc] : 0.f;
#pragma unroll
      for (int r = 0; r < 4; ++r) {
        const int m = mb + r;
        const long off = cbase + (long)m * ldc + nc;
        float vv = acc[i][j][r] + bvv;
        if (RELU) vv = fmaxf(vv, 0.f);
        if (OUT_BF16) cb[off] = f2b(vv);
        else cf[off] = vv;
      }
    }
  }
}

template<int BN_, bool B_, bool R_, bool O_>
static inline void gemmL(hipStream_t st, int M, int N, int K,
                         const bf16* A, int lda, long aHi, long aLo,
                         const bf16* Bt, int ldb, long bHi, long bLo,
                         void* C, int ldc, long cHi, long cLo,
                         int zdiv, int nz, const float* bias)
{
  dim3 g(M / 128, N / BN_, nz);
  gemm_bt<BN_, B_, R_, O_><<<g, dim3(256), 0, st>>>(
      A, Bt, C, bias, M, N, K, lda, ldb, ldc, aHi, aLo, bHi, bLo, cHi, cLo, zdiv);
}

// ---------------------------------------------------------------------------
template<typename ST>
__global__ __launch_bounds__(256) void transpose_to_bf16(
    const ST* __restrict__ in, bf16* __restrict__ out, int R, int C, long sIn, long sOut)
{
  __shared__ bf16 tile[32][33];
  const int z = blockIdx.z;
  in += (long)z * sIn;
  out += (long)z * sOut;
  const int tx = threadIdx.x & 31, ty = threadIdx.x >> 5;
  const int c0 = blockIdx.x * 32, r0 = blockIdx.y * 32;
#pragma unroll
  for (int i = 0; i < 4; ++i)
    tile[ty + i * 8][tx] = f2b(ldf(in + (long)(r0 + ty + i * 8) * C + c0 + tx));
  __syncthreads();
#pragma unroll
  for (int i = 0; i < 4; ++i)
    out[(long)(c0 + ty + i * 8) * R + r0 + tx] = tile[tx][ty + i * 8];
}

__global__ __launch_bounds__(256) void cast4_k(
    const float* __restrict__ in, bf16* __restrict__ out, long n4)
{
  long i = (long)blockIdx.x * 256 + threadIdx.x;
  const long st = (long)gridDim.x * 256;
  for (; i < n4; i += st) {
    const float4 v = ((const float4*)in)[i];
    bf16* o = out + i * 4;
    o[0] = f2b(v.x); o[1] = f2b(v.y); o[2] = f2b(v.z); o[3] = f2b(v.w);
  }
}

__global__ __launch_bounds__(256) void fill_sentinel(float* __restrict__ out, long n)
{
  long i = (long)blockIdx.x * 256 + threadIdx.x;
  const long st = (long)gridDim.x * 256;
  for (; i < n; i += st) out[i] = 1.0e6f;
}

// in-place softmax over 1024-wide rows of bf16 scores; arg = (S + v[t]) * scale
__global__ __launch_bounds__(256) void softmax_rows(
    bf16* __restrict__ S, const float* __restrict__ v, float scale, int causal)
{
  const int r = blockIdx.x * 4 + (threadIdx.x >> 6);
  const int l = threadIdx.x & 63;
  const int zl = r >> 10, s = r & 1023;
  bf16* row = S + (long)r * 1024;
  const float* vp = v + (zl >> 2) * 4096 + (zl & 3) * 1024;
  const int t0 = l * 16;
  bf16x8* rp = (bf16x8*)(row + t0);
  const bf16x8 a0 = rp[0], a1 = rp[1];
  float xx[16];
#pragma unroll
  for (int j = 0; j < 8; ++j) { xx[j] = (float)a0[j]; xx[8 + j] = (float)a1[j]; }
  float mx = -3.4e38f;
#pragma unroll
  for (int k = 0; k < 16; ++k) {
    const int tt = t0 + k;
    float val = (xx[k] + vp[tt]) * scale;
    if (causal && tt > s) val = -3.4e38f;
    xx[k] = val;
    mx = fmaxf(mx, val);
  }
#pragma unroll
  for (int d = 1; d < 64; d <<= 1) mx = fmaxf(mx, __shfl_xor(mx, d));
  float sum = 0.f;
#pragma unroll
  for (int k = 0; k < 16; ++k) {
    const float e = (xx[k] > -1e37f) ? __expf(xx[k] - mx) : 0.f;
    xx[k] = e;
    sum += e;
  }
#pragma unroll
  for (int d = 1; d < 64; d <<= 1) sum += __shfl_xor(sum, d);
  const float inv = 1.f / sum;
  bf16x8 r0v, r1v;
#pragma unroll
  for (int j = 0; j < 8; ++j) {
    r0v[j] = (__bf16)(xx[j] * inv);
    r1v[j] = (__bf16)(xx[8 + j] * inv);
  }
  rp[0] = r0v;
  rp[1] = r1v;
}

// fused: sum split-K partials + beff + residual -> LayerNorm -> bf16/fp32 out
__global__ __launch_bounds__(256) void ln_fused(
    const float* __restrict__ parts, long zstride, int nz,
    const float* __restrict__ beff, const float* __restrict__ resF,
    const bf16* __restrict__ resB, const float* __restrict__ g,
    const float* __restrict__ b, bf16* __restrict__ outB, float* __restrict__ outF)
{
  const int m = blockIdx.x * 4 + (threadIdx.x >> 6);
  const int l = threadIdx.x & 63;
  float vv[8];
  float s = 0.f;
#pragma unroll
  for (int i = 0; i < 8; ++i) {
    const int c = i * 64 + l;
    float acc = beff[c];
    if (resF) acc += resF[(long)m * 512 + c];
    else acc += b2f(resB[(long)m * 512 + c]);
    for (int zz = 0; zz < nz; ++zz) acc += parts[zz * zstride + (long)m * 512 + c];
    vv[i] = acc;
    s += acc;
  }
#pragma unroll
  for (int d = 1; d < 64; d <<= 1) s += __shfl_xor(s, d);
  const float mean = s * (1.f / 512.f);
  float vs = 0.f;
#pragma unroll
  for (int i = 0; i < 8; ++i) { const float dv = vv[i] - mean; vs += dv * dv; }
#pragma unroll
  for (int d = 1; d < 64; d <<= 1) vs += __shfl_xor(vs, d);
  const float rstd = rsqrtf(vs * (1.f / 512.f) + 1e-5f);
#pragma unroll
  for (int i = 0; i < 8; ++i) {
    const int c = i * 64 + l;
    const float y = (vv[i] - mean) * rstd * g[c] + b[c];
    if (outB) outB[(long)m * 512 + c] = f2b(y);
    if (outF) outF[(long)m * 512 + c] = y;
  }
}

// ---- parallel bias-fold kernels (was beff_k / wkbq_k, latency-bound) -------
__global__ void beff_init_k(const float* __restrict__ bf_, float* __restrict__ beff)
{
  const int e = blockIdx.x * 256 + threadIdx.x;
  if (e < 512) beff[e] = bf_[e];
}

// beff[e] += sum_hg bo[hg]*wf[hg,e]; 32 blocks x 128 rows, coalesced rows
__global__ __launch_bounds__(256) void beff_wf_k(
    const float* __restrict__ bo, const float* __restrict__ wf, float* __restrict__ beff)
{
  const int t = threadIdx.x;
  const int r0 = blockIdx.x * 128;
  float s0 = 0.f, s1 = 0.f;
  for (int r = 0; r < 128; ++r) {
    const float bb = bo[r0 + r];
    const float* row = wf + (long)(r0 + r) * 512;
    s0 += bb * row[t];
    s1 += bb * row[t + 256];
  }
  atomicAdd(&beff[t], s0);
  atomicAdd(&beff[t + 256], s1);
}

// beff[e] += sum_hf bv[hf]*W2t[e,hf]; one wave per e, coalesced row read
__global__ __launch_bounds__(256) void beff_w2_k(
    const float* __restrict__ bv, const bf16* __restrict__ W2t, float* __restrict__ beff)
{
  const int e = blockIdx.x * 4 + (threadIdx.x >> 6);
  const int l = threadIdx.x & 63;
  const bf16* row = W2t + (long)e * 4096;
  float s = 0.f;
#pragma unroll
  for (int j = 0; j < 8; ++j) {
    const int hf = j * 512 + l * 8;
    const bf16x8 wv = *(const bf16x8*)(row + hf);
    const float4 b0 = *(const float4*)(bv + hf);
    const float4 b1 = *(const float4*)(bv + hf + 4);
    s += (float)wv[0] * b0.x + (float)wv[1] * b0.y + (float)wv[2] * b0.z + (float)wv[3] * b0.w;
    s += (float)wv[4] * b1.x + (float)wv[5] * b1.y + (float)wv[6] * b1.z + (float)wv[7] * b1.w;
  }
#pragma unroll
  for (int d = 1; d < 64; d <<= 1) s += __shfl_xor(s, d);
  if (l == 0) atomicAdd(&beff[e], s);
}

// wkbq[h][d] = sum_f wk[h,d,f]*bq[h,f]; one wave per (h,d)
__global__ __launch_bounds__(256) void wkbq_k(
    const float* __restrict__ wk, const float* __restrict__ bq, float* __restrict__ o)
{
  const int id = blockIdx.x * 4 + (threadIdx.x >> 6);  // 4096 waves
  const int l = threadIdx.x & 63;
  const int h = id >> 9, d = id & 511;
  const float* wp = wk + (long)h * 262144 + (long)d * 512 + l * 8;
  const float* bp = bq + h * 512 + l * 8;
  float s = 0.f;
#pragma unroll
  for (int j = 0; j < 2; ++j) {
    const float4 a = *(const float4*)(wp + j * 4);
    const float4 b = *(const float4*)(bp + j * 4);
    s += a.x * b.x + a.y * b.y + a.z * b.z + a.w * b.w;
  }
#pragma unroll
  for (int dd = 1; dd < 64; dd <<= 1) s += __shfl_xor(s, dd);
  if (l == 0) o[id] = s;
}

// v[h][m] = sum_d kvB[m,d] * wkbq[h,d]
__global__ __launch_bounds__(256) void rank1_v(
    const bf16* __restrict__ kvB, const float* __restrict__ wkbq, float* __restrict__ v)
{
  const int m = blockIdx.x * 4 + (threadIdx.x >> 6);
  const int l = threadIdx.x & 63;
  const bf16x8 row = *(const bf16x8*)(kvB + (long)m * 512 + l * 8);
  float rf[8];
#pragma unroll
  for (int j = 0; j < 8; ++j) rf[j] = (float)row[j];
  for (int h = 0; h < 8; ++h) {
    const float* wp = wkbq + h * 512 + l * 8;
    float p = 0.f;
#pragma unroll
    for (int j = 0; j < 8; ++j) p += rf[j] * wp[j];
#pragma unroll
    for (int d = 1; d < 64; d <<= 1) p += __shfl_xor(p, d);
    if (l == 0) v[(long)h * 4096 + m] = p;
  }
}

// ---------------------------------------------------------------------------
extern "C" void kernel_launch(void* const* d_in, const int* in_sizes, int n_in,
                              void* d_out, int out_size, void* d_ws, size_t ws_size,
                              hipStream_t stream)
{
  (void)in_sizes; (void)n_in;
  const float* x = (const float*)d_in[0];
  const float* enc = (const float*)d_in[1];
  const float* ln_g[3] = {(const float*)d_in[22], (const float*)d_in[24], (const float*)d_in[26]};
  const float* ln_b[3] = {(const float*)d_in[23], (const float*)d_in[25], (const float*)d_in[27]};
  const float* fc1_w = (const float*)d_in[28];
  const float* fc1_b = (const float*)d_in[29];
  const float* fc2_w = (const float*)d_in[30];
  const float* fc2_b = (const float*)d_in[31];

  const float scale = 0.044194173824159216f;  // 1/sqrt(512)
  char* base = (char*)d_ws;
  const long MB = 1024 * 1024;

  // ---- layout (113 MB) ----
  bf16* Xb    = (bf16*)(base + 0 * MB);
  bf16* Eb    = (bf16*)(base + 4 * MB);
  bf16* x1b   = (bf16*)(base + 8 * MB);
  bf16* x2b   = (bf16*)(base + 12 * MB);
  bf16* fc1T  = (bf16*)(base + 16 * MB);
  bf16* fc2T  = (bf16*)(base + 18 * MB);
  float* vbuf = (float*)(base + 20 * MB);
  float* wkbq = (float*)(base + 20 * MB + 256 * 1024);
  float* beff = (float*)(base + 20 * MB + 512 * 1024);
  bf16* XT    = (bf16*)(base + 21 * MB);
  bf16* WqkT  = (bf16*)(base + 25 * MB);
  bf16* W3cat = (bf16*)(base + 29 * MB);
  char* Treg  = base + 33 * MB;
  char* screg = base + 65 * MB;
  char* axreg = base + 81 * MB;

  bf16* T      = (bf16*)Treg;
  float* parts = (float*)Treg;
  bf16* scores = (bf16*)screg;
  bf16* W2t    = (bf16*)screg;
  bf16* wfT    = (bf16*)(screg + 4 * MB);
  bf16* AX     = (bf16*)axreg;
  bf16* wqB    = (bf16*)axreg;
  bf16* wkB    = (bf16*)(axreg + 4 * MB);
  bf16* wvB    = (bf16*)(axreg + 8 * MB);
  bf16* woB    = (bf16*)(axreg + 12 * MB);
  bf16* Hb     = (bf16*)axreg;

  if (ws_size < (size_t)(113 * MB)) {
    fill_sentinel<<<dim3(2048), dim3(256), 0, stream>>>((float*)d_out, (long)out_size);
    return;
  }

  // ---- global prep ----
  cast4_k<<<dim3(512), dim3(256), 0, stream>>>(x, Xb, 4096L * 512 / 4);
  cast4_k<<<dim3(512), dim3(256), 0, stream>>>(enc, Eb, 4096L * 512 / 4);
  transpose_to_bf16<float><<<dim3(64, 16, 1), dim3(256), 0, stream>>>(fc1_w, fc1T, 512, 2048, 0, 0);
  transpose_to_bf16<float><<<dim3(16, 64, 1), dim3(256), 0, stream>>>(fc2_w, fc2T, 2048, 512, 0, 0);

  auto run_attn = [&](int ib, const bf16* qB, const bf16* kvB,
                      const float* resF, const bf16* resB, int causal,
                      const float* lg, const float* lb, bf16* outB) {
    const float* wq = (const float*)d_in[ib + 0];
    const float* bq = (const float*)d_in[ib + 1];
    const float* wk = (const float*)d_in[ib + 2];
    const float* wv = (const float*)d_in[ib + 4];
    const float* bv = (const float*)d_in[ib + 5];
    const float* wo = (const float*)d_in[ib + 6];
    const float* bo = (const float*)d_in[ib + 7];
    const float* wf = (const float*)d_in[ib + 8];
    const float* bfv = (const float*)d_in[ib + 9];

    cast4_k<<<dim3(512), dim3(256), 0, stream>>>(wq, wqB, 2097152 / 4);
    cast4_k<<<dim3(512), dim3(256), 0, stream>>>(wk, wkB, 2097152 / 4);
    cast4_k<<<dim3(512), dim3(256), 0, stream>>>(wv, wvB, 2097152 / 4);
    cast4_k<<<dim3(512), dim3(256), 0, stream>>>(wo, woB, 2097152 / 4);
    transpose_to_bf16<float><<<dim3(16, 128, 1), dim3(256), 0, stream>>>(wf, wfT, 4096, 512, 0, 0);
    // W2t[e][h*512+f] = sum_g wfT[e][h*512+g] * wo[h][f][g]
    gemmL<64, false, false, true>(stream, 512, 512, 512,
        wfT, 4096, 512, 0, woB, 512, 262144, 0, W2t, 4096, 512, 0, 1, 8, nullptr);
    beff_init_k<<<dim3(2), dim3(256), 0, stream>>>(bfv, beff);
    beff_wf_k<<<dim3(32), dim3(256), 0, stream>>>(bo, wf, beff);
    beff_w2_k<<<dim3(128), dim3(256), 0, stream>>>(bv, W2t, beff);
    // WqkT[h*512+d2][d1] = sum_f wk[h,d2,f] * wq[h,d1,f]
    gemmL<64, false, false, true>(stream, 512, 512, 512,
        wkB, 512, 262144, 0, wqB, 512, 262144, 0, WqkT, 512, 262144, 0, 1, 8, nullptr);
    // W3cat[e][h*512+d] = sum_f W2t[e][h*512+f] * wv[h,d,f]
    gemmL<64, false, false, true>(stream, 512, 512, 512,
        W2t, 4096, 512, 0, wvB, 512, 262144, 0, W3cat, 4096, 512, 0, 1, 8, nullptr);
    wkbq_k<<<dim3(1024), dim3(256), 0, stream>>>(wk, bq, wkbq);
    rank1_v<<<dim3(1024), dim3(256), 0, stream>>>(kvB, wkbq, vbuf);
    transpose_to_bf16<bf16><<<dim3(16, 32, 4), dim3(256), 0, stream>>>(
        kvB, XT, 1024, 512, 524288, 524288);
    // T = qB @ Wqk  [4096, 4096]
    gemmL<128, false, false, true>(stream, 4096, 4096, 512,
        qB, 512, 0, 0, WqkT, 512, 0, 0, T, 4096, 0, 0, 1, 1, nullptr);

    for (int c = 0; c < 4; ++c) {
      gemmL<128, false, false, true>(stream, 1024, 1024, 512,
          T + 2 * c * 512, 4096, 512, 4194304,
          kvB, 512, 0, 524288,
          scores, 1024, 4194304, 1048576, 4, 8, nullptr);
      softmax_rows<<<dim3(2048), dim3(256), 0, stream>>>(
          scores, vbuf + 2 * c * 4096, scale, causal);
      gemmL<64, false, false, true>(stream, 1024, 512, 1024,
          scores, 1024, 4194304, 1048576,
          XT, 1024, 0, 524288,
          AX + 2 * c * 512, 4096, 512, 4194304, 4, 8, nullptr);
    }
    gemmL<64, false, false, false>(stream, 4096, 512, 1024,
        AX, 4096, 1024, 0, W3cat, 4096, 1024, 0,
        parts, 512, 2097152, 0, 1, 4, nullptr);
    ln_fused<<<dim3(1024), dim3(256), 0, stream>>>(
        parts, 2097152, 4, beff, resF, resB, lg, lb, outB, nullptr);
  };

  run_attn(2, Xb, Xb, x, nullptr, 1, ln_g[0], ln_b[0], x1b);
  run_attn(12, x1b, Eb, nullptr, x1b, 0, ln_g[1], ln_b[1], x2b);

  // ---- FFN ----
  gemmL<128, true, true, true>(stream, 4096, 2048, 512,
      x2b, 512, 0, 0, fc1T, 512, 0, 0, Hb, 2048, 0, 0, 1, 1, fc1_b);
  gemmL<64, false, false, false>(stream, 4096, 512, 512,
      Hb, 2048, 512, 0, fc2T, 2048, 512, 0, parts, 512, 2097152, 0, 1, 4, nullptr);
  ln_fused<<<dim3(1024), dim3(256), 0, stream>>>(
      parts, 2097152, 4, fc2_b, nullptr, x2b, ln_g[2], ln_b[2], nullptr, (float*)d_out);
}